// Round 4
// baseline (1160.613 us; speedup 1.0000x reference)
//
#include <hip/hip_runtime.h>
#include <stdint.h>

typedef __bf16 bf16x8 __attribute__((ext_vector_type(8)));
typedef float f32x4 __attribute__((ext_vector_type(4)));

__device__ __forceinline__ unsigned short f2bf(float f) {
    union { float f; uint32_t i; } v;
    v.f = f;
    uint32_t x = v.i;
    return (unsigned short)((x + 0x7FFFu + ((x >> 16) & 1u)) >> 16);  // RNE
}

// async global->LDS, 16B per lane. LDS dest is wave-uniform base + lane*16;
// the GLOBAL source address is per-lane free (this is what enables swizzling).
typedef __attribute__((address_space(3))) unsigned int lds_u32;
typedef __attribute__((address_space(1))) const unsigned int glob_u32;
__device__ __forceinline__ void gld16(const unsigned short* g, unsigned short* l) {
    __builtin_amdgcn_global_load_lds((glob_u32*)g, (lds_u32*)l, 16, 0, 0);
}

typedef __attribute__((address_space(3))) unsigned short lds_us;
__device__ __forceinline__ unsigned ldsaddr(unsigned short* p) {
    return (unsigned)(uintptr_t)(lds_us*)p;   // 32-bit LDS byte address
}

// ---------------------------------------------------------------------------
// All weight prep in ONE launch (range-dispatch on blockIdx.x, 9220 blocks).
// ---------------------------------------------------------------------------
__global__ __launch_bounds__(256) void prep_weights(
    const float* __restrict__ Wq, const float* __restrict__ Wk,
    const float* __restrict__ Wm, const float* __restrict__ W1,
    const float* __restrict__ W2, const float* __restrict__ bq,
    const float* __restrict__ bk,
    unsigned short* __restrict__ wqb, unsigned short* __restrict__ wkb,
    unsigned short* __restrict__ wmb, unsigned short* __restrict__ w1b,
    unsigned short* __restrict__ w2b, float* __restrict__ bqp,
    float* __restrict__ bkp)
{
    const int b = blockIdx.x, t = threadIdx.x;
    if (b < 2048) {
        const float* in = (b < 1024) ? Wq : Wk;
        unsigned short* out = (b < 1024) ? wqb : wkb;
        const int i = ((b & 1023) * 256 + t) * 4;
        const int row = i >> 10, col = i & 1023;
        const float4 v = *(const float4*)(in + ((row & 63) * 16 + (row >> 6)) * 1024 + col);
        out[i + 0] = f2bf(v.x); out[i + 1] = f2bf(v.y);
        out[i + 2] = f2bf(v.z); out[i + 3] = f2bf(v.w);
    } else if (b < 3072) {
        const int i = ((b - 2048) * 256 + t) * 4;
        const int row = i >> 10, c0 = i & 1023;
        const float* r = Wm + (size_t)row * 1024;
#pragma unroll
        for (int j = 0; j < 4; ++j) {
            const int c = c0 + j;
            wmb[i + j] = f2bf(r[(c & 63) * 16 + (c >> 6)]);
        }
    } else if (b < 7168) {
        const int i = ((b - 3072) * 256 + t) * 4;
        const float4 v = *(const float4*)(W1 + i);
        w1b[i + 0] = f2bf(v.x); w1b[i + 1] = f2bf(v.y);
        w1b[i + 2] = f2bf(v.z); w1b[i + 3] = f2bf(v.w);
    } else if (b < 9216) {
        const int i = ((b - 7168) * 256 + t) * 4;
        const float4 v = *(const float4*)(W2 + i);
        w2b[i + 0] = f2bf(v.x); w2b[i + 1] = f2bf(v.y);
        w2b[i + 2] = f2bf(v.z); w2b[i + 3] = f2bf(v.w);
    } else {
        const int o = (b - 9216) * 256 + t;
        const int src = (o & 63) * 16 + (o >> 6);
        bqp[o] = bq[src];
        bkp[o] = bk[src];
    }
}

// ---------------------------------------------------------------------------
// f32 [R][C] -> bf16 [C][R], batched over blockIdx.z (proj).
// ---------------------------------------------------------------------------
__global__ __launch_bounds__(256) void cvt_transpose(
    const float* __restrict__ in, unsigned short* __restrict__ out,
    int R, int C)
{
    __shared__ unsigned short tile[32][33];
    const size_t bo = (size_t)blockIdx.z * R * C;
    const int c0 = blockIdx.x * 32, r0 = blockIdx.y * 32;
    const int tx = threadIdx.x & 31, ty = threadIdx.x >> 5;
#pragma unroll
    for (int i = 0; i < 4; ++i)
        tile[ty + i * 8][tx] = f2bf(in[bo + (size_t)(r0 + ty + i * 8) * C + (c0 + tx)]);
    __syncthreads();
#pragma unroll
    for (int i = 0; i < 4; ++i)
        out[bo + (size_t)(c0 + ty + i * 8) * R + (r0 + tx)] = tile[tx][ty + i * 8];
}

// Fused x + source transpose: z = tensor*4 + batch.
__global__ __launch_bounds__(256) void cvt_transpose_xs(
    const float* __restrict__ x, const float* __restrict__ s,
    unsigned short* __restrict__ xt, unsigned short* __restrict__ st)
{
    __shared__ unsigned short tile[32][33];
    const int z = blockIdx.z;
    const float* in = (z < 4) ? x : s;
    unsigned short* out = (z < 4) ? xt : st;
    const size_t bo = (size_t)(z & 3) * 1024 * 4096;
    const int c0 = blockIdx.x * 32, r0 = blockIdx.y * 32;
    const int tx = threadIdx.x & 31, ty = threadIdx.x >> 5;
#pragma unroll
    for (int i = 0; i < 4; ++i)
        tile[ty + i * 8][tx] = f2bf(in[bo + (size_t)(r0 + ty + i * 8) * 4096 + (c0 + tx)]);
    __syncthreads();
#pragma unroll
    for (int i = 0; i < 4; ++i)
        out[bo + (size_t)(c0 + ty + i * 8) * 1024 + (r0 + tx)] = tile[tx][ty + i * 8];
}

// ---------------------------------------------------------------------------
// OLD 128x128 2-barrier GEMM. Kept ONLY for the kp projection (N'=128 < 256).
// ---------------------------------------------------------------------------
template<int LDA, int LDB, int LDC, int KD, int SPLIT, bool CONCAT>
__global__ __launch_bounds__(256) void gemm_bt(
    const unsigned short* __restrict__ A,
    const unsigned short* __restrict__ A2, int K1,
    const unsigned short* __restrict__ BT,
    unsigned short* __restrict__ C, float* __restrict__ Cf,
    long long strideA, long long strideB, long long strideC,
    const float* __restrict__ bias_m,
    const float* __restrict__ bias_n,
    const float* __restrict__ bn_g,
    const float* __restrict__ bn_b,
    const float* __restrict__ bn_mu,
    const float* __restrict__ bn_var)
{
    constexpr int KPB = KD / SPLIT;
    __shared__ __align__(16) unsigned short As[128 * 64];
    __shared__ __align__(16) unsigned short Bs[128 * 64];

    const int z = blockIdx.z;
    const int batch = z / SPLIT;
    const int kbase = (z % SPLIT) * KPB;
    const int m0 = blockIdx.y * 128, n0 = blockIdx.x * 128;
    const unsigned short* Ab  = A + (size_t)batch * strideA;
    const unsigned short* A2b = CONCAT ? A2 + (size_t)batch * strideA
                                       : (const unsigned short*)0;
    const unsigned short* Bb = BT + (size_t)batch * strideB;

    const int t = threadIdx.x;
    const int lane = t & 63, wid = t >> 6;
    const int wm = wid >> 1, wn = wid & 1;
    const int r16 = lane & 15, quad = lane >> 4;

    f32x4 acc[4][4];
    const f32x4 zf = {0.f, 0.f, 0.f, 0.f};
#pragma unroll
    for (int i = 0; i < 4; ++i)
#pragma unroll
        for (int j = 0; j < 4; ++j) acc[i][j] = zf;

    for (int kt = kbase; kt < kbase + KPB; kt += 64) {
        const unsigned short* Asrc = Ab;
        int kk = kt;
        if (CONCAT && kt >= K1) { Asrc = A2b; kk = kt - K1; }
#pragma unroll
        for (int i = 0; i < 4; ++i) {
            const int p = i * 256 + t;
            const int row = p >> 3, slot = p & 7;
            const int kc = (slot ^ (row & 7)) * 8;
            gld16(&Asrc[(size_t)(m0 + row) * LDA + kk + kc], &As[p * 8]);
            gld16(&Bb[(size_t)(n0 + row) * LDB + kt + kc], &Bs[p * 8]);
        }
        __syncthreads();
#pragma unroll
        for (int s = 0; s < 2; ++s) {
            bf16x8 af[4], bfb[4];
#pragma unroll
            for (int i = 0; i < 4; ++i) {
                const int ra = wm * 64 + i * 16 + r16;
                const int rb = wn * 64 + i * 16 + r16;
                af[i]  = *(const bf16x8*)&As[(ra * 8 + ((s * 4 + quad) ^ (ra & 7))) * 8];
                bfb[i] = *(const bf16x8*)&Bs[(rb * 8 + ((s * 4 + quad) ^ (rb & 7))) * 8];
            }
#pragma unroll
            for (int mi = 0; mi < 4; ++mi)
#pragma unroll
                for (int ni = 0; ni < 4; ++ni)
                    acc[mi][ni] = __builtin_amdgcn_mfma_f32_16x16x32_bf16(
                        af[mi], bfb[ni], acc[mi][ni], 0, 0, 0);
        }
        __syncthreads();
    }

    unsigned short* Cb = C ? C + (size_t)z * strideC : (unsigned short*)0;
    float* Cfb = Cf ? Cf + (size_t)z * strideC : (float*)0;
    const bool has_bn = (bn_g != 0);
#pragma unroll
    for (int ni = 0; ni < 4; ++ni) {
        const int gn = n0 + wn * 64 + ni * 16 + r16;
        const float addn = bias_n ? bias_n[gn] : 0.f;
        float g = 1.f, bb = 0.f, mu = 0.f, rstd = 1.f;
        if (has_bn) {
            g = bn_g[gn]; bb = bn_b[gn]; mu = bn_mu[gn];
            rstd = rsqrtf(bn_var[gn] + 1e-3f);
        }
#pragma unroll
        for (int mi = 0; mi < 4; ++mi) {
            const int gm0 = m0 + wm * 64 + mi * 16 + quad * 4;
#pragma unroll
            for (int r = 0; r < 4; ++r) {
                float v = acc[mi][ni][r] + addn;
                if (bias_m) v += bias_m[gm0 + r];
                if (has_bn) { v = g * (v - mu) * rstd + bb; v = fmaxf(v, 0.f); }
                const size_t idx = (size_t)(gm0 + r) * LDC + gn;
                if (Cfb) Cfb[idx] = v;
                else     Cb[idx]  = f2bf(v);
            }
        }
    }
}

// ---------------------------------------------------------------------------
// 256x256 GEMM v4: inline-asm ds_read K-loop (8 waves 2Mx4N, BK=64, dbuf).
//
// r1-r3 post-mortem: MfmaUtil pinned at ~38% across 3 phase/vmcnt schedules.
// Theory: LLVM's waitcnt pass sees the C++ ds_reads and conservatively
// orders them against in-flight global_load_lds DMA (loop-carried, same
// LDS), inserting its own near-drain vmcnt before every read cluster --
// manual counted vmcnt never governs. Fix (HK technique): ds_read_b128 as
// inline asm with precomputed per-thread base VGPRs + literal offset:
// immediates -> opaque to the waitcnt pass, zero address VALU in the loop.
//
// Tile split into 2 ks-half bodies (12 reads + 32 MFMA each, 48 frag VGPRs
// live -> ~2 waves/SIMD kept). 3 barriers per K-tile; reads of the next
// body issue straight after own MFMA (no barrier between) -> wave slip
// overlaps LDS service with MFMA. One full-tile stage (8 gld) per K-tile
// at the odd body after BAR1 (write-safe: all reads of that buf drained);
// vmcnt(8) then confirms the PREVIOUS tile's stage before BAR2 publishes
// it. Safety: rule #18 sched_barrier(0) after every lgkmcnt(0).
// ---------------------------------------------------------------------------
#define BAR   __builtin_amdgcn_s_barrier()
#define LGKM0 asm volatile("s_waitcnt lgkmcnt(0)" ::: "memory")
#define SB0   __builtin_amdgcn_sched_barrier(0)
#define PRIO1 __builtin_amdgcn_s_setprio(1)
#define PRIO0 __builtin_amdgcn_s_setprio(0)
#define VMC8  asm volatile("s_waitcnt vmcnt(8)" ::: "memory")
#define VMC0  asm volatile("s_waitcnt vmcnt(0)" ::: "memory")

#define ST_A(dst, kt, i0, i1) do {                                          \
    const unsigned short* S_ = Ab; long long kk_ = (kt);                    \
    if (CONCAT && (kt) >= K1) { S_ = A2b; kk_ = (kt) - K1; }                \
    gld16(&S_[offA[i0] + kk_], (dst) + po[i0]);                             \
    gld16(&S_[offA[i1] + kk_], (dst) + po[i1]); } while (0)

#define ST_B(dst, kt, i0, i1) do {                                          \
    gld16(&Bb[offB[i0] + (kt)], (dst) + po[i0]);                            \
    gld16(&Bb[offB[i1] + (kt)], (dst) + po[i1]); } while (0)

#define DSR(d, b_, imm)                                                     \
    asm volatile("ds_read_b128 %0, %1 offset:" #imm                         \
                 : "=v"(d) : "v"(b_) : "memory")

#define RD12(AB, BB) do {                                                   \
    DSR(f0, AB, 0);    DSR(f1, AB, 2048);                                   \
    DSR(f2, AB, 4096); DSR(f3, AB, 6144);                                   \
    DSR(f4, AB, 8192); DSR(f5, AB, 10240);                                  \
    DSR(f6, AB, 12288); DSR(f7, AB, 14336);                                 \
    DSR(g0, BB, 0);    DSR(g1, BB, 2048);                                   \
    DSR(g2, BB, 4096); DSR(g3, BB, 6144); } while (0)

#define MM(i, j, ff, gg)                                                    \
    acc[i][j] = __builtin_amdgcn_mfma_f32_16x16x32_bf16(ff, gg, acc[i][j], 0, 0, 0)

#define MFMA32 do {                                                         \
    MM(0,0,f0,g0); MM(0,1,f0,g1); MM(0,2,f0,g2); MM(0,3,f0,g3);             \
    MM(1,0,f1,g0); MM(1,1,f1,g1); MM(1,2,f1,g2); MM(1,3,f1,g3);             \
    MM(2,0,f2,g0); MM(2,1,f2,g1); MM(2,2,f2,g2); MM(2,3,f2,g3);             \
    MM(3,0,f3,g0); MM(3,1,f3,g1); MM(3,2,f3,g2); MM(3,3,f3,g3);             \
    MM(4,0,f4,g0); MM(4,1,f4,g1); MM(4,2,f4,g2); MM(4,3,f4,g3);             \
    MM(5,0,f5,g0); MM(5,1,f5,g1); MM(5,2,f5,g2); MM(5,3,f5,g3);             \
    MM(6,0,f6,g0); MM(6,1,f6,g1); MM(6,2,f6,g2); MM(6,3,f6,g3);             \
    MM(7,0,f7,g0); MM(7,1,f7,g1); MM(7,2,f7,g2); MM(7,3,f7,g3); } while (0)

// even body: ks0 reads of current tile; 1 barrier; MFMA quadrants (all n).
#define BODY_E(XV, AK, BK) do {                                             \
    RD12(AK, BK);                                                           \
    LGKM0; SB0; BAR;                                                        \
    PRIO1; MFMA32; PRIO0;                                                   \
} while (0)

// odd body: ks1 reads; BAR1 (all cur reads done) -> stage tile X+2 into
// cur buf; vmcnt(8) confirms tile X+1's stage; BAR2 publishes; MFMA.
#define BODY_O(XV, AK, BK, AD, BD) do {                                     \
    RD12(AK, BK);                                                           \
    LGKM0; SB0; BAR;                                                        \
    if ((XV) + 2 < nt) {                                                    \
        const int kt2_ = ((XV) + 2) * 64;                                   \
        ST_A(AD, kt2_, 0, 2); ST_A(AD, kt2_, 1, 3);                         \
        ST_B(BD, kt2_, 0, 1); ST_B(BD, kt2_, 2, 3);                         \
        VMC8;                                                               \
    } else { VMC0; }                                                        \
    SB0; BAR;                                                               \
    PRIO1; MFMA32; PRIO0;                                                   \
} while (0)

template<int LDA, int LDB, int LDC, int KD, bool CONCAT>
__global__ __launch_bounds__(512, 2) void gemm256(
    const unsigned short* __restrict__ A,
    const unsigned short* __restrict__ A2, int K1,
    const unsigned short* __restrict__ BT,
    unsigned short* __restrict__ C, float* __restrict__ Cf,
    long long strideA, long long strideB, long long strideC,
    const float* __restrict__ bias_m,
    const float* __restrict__ bias_n,
    const float* __restrict__ bn_g,
    const float* __restrict__ bn_b,
    const float* __restrict__ bn_mu,
    const float* __restrict__ bn_var)
{
    static_assert(KD % 128 == 0, "nt must be even");
    constexpr int nt = KD / 64;
    constexpr int TILE = 256 * 64;               // elems = 32 KB
    __shared__ __align__(16) unsigned short Ls[4 * TILE];  // A0|A1|B0|B1
    unsigned short* A0 = Ls;
    unsigned short* A1 = Ls + TILE;
    unsigned short* B0 = Ls + 2 * TILE;
    unsigned short* B1 = Ls + 3 * TILE;

    const int batch = blockIdx.z;
    // Bijective XCD-contiguous tile remap (all grids here have nwg % 8 == 0).
    const int gx = gridDim.x;
    const int nwg = gx * gridDim.y;
    int flat = blockIdx.y * gx + blockIdx.x;
    flat = (flat & 7) * (nwg >> 3) + (flat >> 3);
    const int n0 = (flat % gx) * 256;
    const int m0 = (flat / gx) * 256;

    const unsigned short* Ab  = A + (size_t)batch * strideA;
    const unsigned short* A2b = CONCAT ? A2 + (size_t)batch * strideA
                                       : (const unsigned short*)0;
    const unsigned short* Bb  = BT + (size_t)batch * strideB;

    const int t = threadIdx.x;
    const int lane = t & 63, wid = t >> 6;
    const int wm = wid >> 2, wn = wid & 3;       // 2 x 4 wave grid
    const int r16 = lane & 15, quad = lane >> 4;

    // Precomputed staging offsets (statically indexed only).
    long long offA[4], offB[4];
    int po[4];
#pragma unroll
    for (int i = 0; i < 4; ++i) {
        const int p = i * 512 + t, row = p >> 3;
        const int kc = ((p & 7) ^ (row & 7)) * 8;
        po[i] = p * 8;
        offA[i] = (long long)(m0 + row) * LDA + kc;
        offB[i] = (long long)(n0 + row) * LDB + kc;
    }

    // Per-thread LDS read base addresses (byte): 8 VGPRs, loop-invariant.
    // read byte addr = base + (mh*8192 + mi*2048) [A] / (j*2048) [B].
    const unsigned lb = ldsaddr(Ls);
    const unsigned x0 = (unsigned)((quad ^ (r16 & 7)) * 16);
    const unsigned x1 = (unsigned)(((4 + quad) ^ (r16 & 7)) * 16);
    const unsigned rowa = lb + (unsigned)((wm * 128 + r16) * 128);
    const unsigned rowb = lb + 65536u + (unsigned)((wn * 64 + r16) * 128);
    const unsigned a_k0_0 = rowa + x0,           a_k1_0 = rowa + x1;
    const unsigned a_k0_1 = rowa + 32768u + x0,  a_k1_1 = rowa + 32768u + x1;
    const unsigned b_k0_0 = rowb + x0,           b_k1_0 = rowb + x1;
    const unsigned b_k0_1 = rowb + 32768u + x0,  b_k1_1 = rowb + 32768u + x1;

    f32x4 acc[8][4];
    const f32x4 zf = {0.f, 0.f, 0.f, 0.f};
#pragma unroll
    for (int i = 0; i < 8; ++i)
#pragma unroll
        for (int j = 0; j < 4; ++j) acc[i][j] = zf;

    bf16x8 f0, f1, f2, f3, f4, f5, f6, f7, g0, g1, g2, g3;

    // Prologue: stage T0 (8 gld) + T1 (8 gld); vmcnt(8) = own T0 done;
    // barrier publishes all waves' T0.
    ST_A(A0, 0, 0, 2);  ST_A(A0, 0, 1, 3);
    ST_B(B0, 0, 0, 1);  ST_B(B0, 0, 2, 3);
    ST_A(A1, 64, 0, 2); ST_A(A1, 64, 1, 3);
    ST_B(B1, 64, 0, 1); ST_B(B1, 64, 2, 3);
    VMC8; SB0; BAR;

#pragma unroll 1
    for (int X2 = 0; X2 < nt; X2 += 2) {
        BODY_E(X2,     a_k0_0, b_k0_0);
        BODY_O(X2,     a_k1_0, b_k1_0, A0, B0);
        BODY_E(X2 + 1, a_k0_1, b_k0_1);
        BODY_O(X2 + 1, a_k1_1, b_k1_1, A1, B1);
    }

    unsigned short* Cb = C ? C + (size_t)batch * strideC : (unsigned short*)0;
    float* Cfb = Cf ? Cf + (size_t)batch * strideC : (float*)0;
    const bool has_bn = (bn_g != 0);

    // Per-ni column params hoisted; ni innermost so both 32B halves of each
    // 64B line are written back-to-back (write-combining; bf16 C path).
    float addn4[4], g4[4], b4[4], mu4[4], rs4[4];
#pragma unroll
    for (int ni = 0; ni < 4; ++ni) {
        const int gn = n0 + wn * 64 + ni * 16 + r16;
        addn4[ni] = bias_n ? bias_n[gn] : 0.f;
        if (has_bn) {
            g4[ni] = bn_g[gn]; b4[ni] = bn_b[gn]; mu4[ni] = bn_mu[gn];
            rs4[ni] = rsqrtf(bn_var[gn] + 1e-3f);
        }
    }
#pragma unroll
    for (int mi = 0; mi < 8; ++mi) {
        const int gm0 = m0 + wm * 128 + mi * 16 + quad * 4;
#pragma unroll
        for (int r = 0; r < 4; ++r) {
            const float bm_ = bias_m ? bias_m[gm0 + r] : 0.f;
            const size_t rowc = (size_t)(gm0 + r) * LDC + n0 + wn * 64 + r16;
#pragma unroll
            for (int ni = 0; ni < 4; ++ni) {
                float v = acc[mi][ni][r] + addn4[ni] + bm_;
                if (has_bn) {
                    v = g4[ni] * (v - mu4[ni]) * rs4[ni] + b4[ni];
                    v = fmaxf(v, 0.f);
                }
                if (Cfb) Cfb[rowc + ni * 16] = v;
                else     Cb[rowc + ni * 16]  = f2bf(v);
            }
        }
    }
}

#undef BODY_O
#undef BODY_E
#undef MFMA32
#undef MM
#undef RD12
#undef DSR
#undef ST_B
#undef ST_A
#undef VMC0
#undef VMC8
#undef PRIO0
#undef PRIO1
#undef SB0
#undef LGKM0
#undef BAR

// kp split-K reduce: kpb[b][j] = bf16( sum_p acc[b*8+p][j] )
__global__ __launch_bounds__(256) void reduce_kp(
    const float* __restrict__ acc, unsigned short* __restrict__ kpb)
{
    const int j = (blockIdx.x * 256 + threadIdx.x) * 4;
    const int b = j >> 17, jj = j & 131071;
    const float* base = acc + (size_t)b * 8 * 131072 + jj;
    float4 s = *(const float4*)base;
#pragma unroll
    for (int p = 1; p < 8; ++p) {
        const float4 v = *(const float4*)(base + (size_t)p * 131072);
        s.x += v.x; s.y += v.y; s.z += v.z; s.w += v.w;
    }
    kpb[j + 0] = f2bf(s.x); kpb[j + 1] = f2bf(s.y);
    kpb[j + 2] = f2bf(s.z); kpb[j + 3] = f2bf(s.w);
}

// ---------------------------------------------------------------------------
// MFMA flash-attention (unchanged; channel order o' = h*64+dh).
// ---------------------------------------------------------------------------
__global__ __launch_bounds__(256) void attn_fused(
    const unsigned short* __restrict__ qT,
    const unsigned short* __restrict__ kp,
    unsigned short* __restrict__ msgT)
{
    constexpr int QS = 72, KS = 72, VS = 136, PS = 136;
    __shared__ __align__(16) unsigned short QKP[128 * QS + 128 * KS];
    __shared__ __align__(16) unsigned short Vs[64 * VS];
    unsigned short* Qs = QKP;
    unsigned short* Ks = QKP + 128 * QS;
    unsigned short* Ps = QKP;

    const int t = threadIdx.x;
    const int lane = t & 63, w = t >> 6;
    const int r16 = lane & 15, quad = lane >> 4;
    const int h = blockIdx.y, n0 = blockIdx.x * 128;
    const size_t b = blockIdx.z;

    const unsigned short* qbase = qT + (b * 4096 + n0) * 1024 + h * 64;
    const unsigned short* kbase = kp + (b * 1024 + h * 64) * 128;

#pragma unroll
    for (int i = 0; i < 4; ++i) {
        const int c = i * 256 + t;
        const int n = c >> 3, dh0 = (c & 7) * 8;
        *(int4*)&Qs[n * QS + dh0] = *(const int4*)&qbase[(size_t)n * 1024 + dh0];
    }
#pragma unroll
    for (int i = 0; i < 4; ++i) {
        const int c = i * 256 + t;
        const int kkq = c & 3, dh = (c >> 2) & 63, kkh = c >> 8;
        const int kk0 = kkh * 32 + kkq * 8;
        const bf16x8 v = *(const bf16x8*)&kbase[(size_t)dh * 128 + kk0];
        *(bf16x8*)&Vs[dh * VS + kk0] = v;
        const unsigned short* vs = (const unsigned short*)&v;
#pragma unroll
        for (int j = 0; j < 8; ++j) Ks[(kk0 + j) * KS + dh] = vs[j];
    }
    __syncthreads();

    f32x4 S[2][8];
    const f32x4 zf = {0.f, 0.f, 0.f, 0.f};
#pragma unroll
    for (int mi = 0; mi < 2; ++mi)
#pragma unroll
        for (int ni = 0; ni < 8; ++ni) S[mi][ni] = zf;

    bf16x8 aq[2][2];
#pragma unroll
    for (int mi = 0; mi < 2; ++mi)
#pragma unroll
        for (int ks = 0; ks < 2; ++ks)
            aq[mi][ks] = *(const bf16x8*)&Qs[(w * 32 + mi * 16 + r16) * QS + ks * 32 + quad * 8];
#pragma unroll
    for (int ni = 0; ni < 8; ++ni) {
        const bf16x8 b0 = *(const bf16x8*)&Ks[(ni * 16 + r16) * KS + quad * 8];
        const bf16x8 b1 = *(const bf16x8*)&Ks[(ni * 16 + r16) * KS + 32 + quad * 8];
#pragma unroll
        for (int mi = 0; mi < 2; ++mi) {
            S[mi][ni] = __builtin_amdgcn_mfma_f32_16x16x32_bf16(aq[mi][0], b0, S[mi][ni], 0, 0, 0);
            S[mi][ni] = __builtin_amdgcn_mfma_f32_16x16x32_bf16(aq[mi][1], b1, S[mi][ni], 0, 0, 0);
        }
    }

    __syncthreads();

    float linv[2][4];
#pragma unroll
    for (int mi = 0; mi < 2; ++mi) {
        float e[8][4];
        float rs0 = 0.f, rs1 = 0.f, rs2 = 0.f, rs3 = 0.f;
#pragma unroll
        for (int ni = 0; ni < 8; ++ni) {
            e[ni][0] = __expf(S[mi][ni][0] * 0.125f); rs0 += e[ni][0];
            e[ni][1] = __expf(S[mi][ni][1] * 0.125f); rs1 += e[ni][1];
            e[ni][2] = __expf(S[mi][ni][2] * 0.125f); rs2 += e[ni][2];
            e[ni][3] = __expf(S[mi][ni][3] * 0.125f); rs3 += e[ni][3];
        }
        float rs[4] = {rs0, rs1, rs2, rs3};
#pragma unroll
        for (int r = 0; r < 4; ++r) {
            float s = rs[r];
            s += __shfl_xor(s, 1); s += __shfl_xor(s, 2);
            s += __shfl_xor(s, 4); s += __shfl_xor(s, 8);
            linv[mi][r] = 1.f / s;
        }
#pragma unroll
        for (int ni = 0; ni < 8; ++ni)
#pragma unroll
            for (int r = 0; r < 4; ++r)
                Ps[(w * 32 + mi * 16 + quad * 4 + r) * PS + ni * 16 + r16] = f2bf(e[ni][r]);
    }
    __syncthreads();

    f32x4 O[2][4];
#pragma unroll
    for (int mi = 0; mi < 2; ++mi)
#pragma unroll
        for (int ni = 0; ni < 4; ++ni) O[mi][ni] = zf;

    bf16x8 ap[2][4];
#pragma unroll
    for (int mi = 0; mi < 2; ++mi)
#pragma unroll
        for (int ks = 0; ks < 4; ++ks)
            ap[mi][ks] = *(const bf16x8*)&Ps[(w * 32 + mi * 16 + r16) * PS + ks * 32 + quad * 8];
#pragma unroll
    for (int ni = 0; ni < 4; ++ni)
#pragma unroll
        for (int ks = 0; ks < 4; ++ks) {
            const bf16x8 bv = *(const bf16x8*)&Vs[(ni * 16 + r16) * VS + ks * 32 + quad * 8];
#pragma unroll
            for (int mi = 0; mi < 2; ++mi)
                O[mi][ni] = __builtin_amdgcn_mfma_f32_16x16x32_bf16(ap[mi][ks], bv, O[mi][ni], 0, 0, 0);
        }

    unsigned short* ob = msgT + (b * 4096 + n0) * 1024 + h * 64;
#pragma unroll
    for (int mi = 0; mi < 2; ++mi)
#pragma unroll
        for (int ni = 0; ni < 4; ++ni)
#pragma unroll
            for (int r = 0; r < 4; ++r)
                ob[(size_t)(w * 32 + mi * 16 + quad * 4 + r) * 1024 + ni * 16 + r16] =
                    f2bf(O[mi][ni][r] * linv[mi][r]);
}

// ---------------------------------------------------------------------------
extern "C" void kernel_launch(void* const* d_in, const int* in_sizes, int n_in,
                              void* d_out, int out_size, void* d_ws, size_t ws_size,
                              hipStream_t stream)
{
    (void)in_sizes; (void)n_in; (void)out_size; (void)ws_size;
    const float* x    = (const float*)d_in[0];
    const float* srcp = (const float*)d_in[1];
    const float* Wq   = (const float*)d_in[2];
    const float* bq   = (const float*)d_in[3];
    const float* Wk   = (const float*)d_in[4];
    const float* bk   = (const float*)d_in[5];
    const float* proj = (const float*)d_in[6];
    const float* Wm   = (const float*)d_in[7];
    const float* bm   = (const float*)d_in[8];
    const float* W1   = (const float*)d_in[9];
    const float* b1   = (const float*)d_in[10];
    const float* gam  = (const float*)d_in[11];
    const float* bet  = (const float*)d_in[12];
    const float* mu   = (const float*)d_in[13];
    const float* var  = (const float*)d_in[14];
    const float* W2   = (const float*)d_in[15];
    const float* b2   = (const float*)d_in[16];
    float* out = (float*)d_out;
    unsigned short* ws = (unsigned short*)d_ws;

    const long long E = 16777216LL;  // 4*4096*1024
    unsigned short* xt  = ws;
    unsigned short* st  = xt + E;
    unsigned short* qt  = st + E;
    unsigned short* kc  = qt + E;
    unsigned short* ht  = kc + E;
    unsigned short* pT  = ht + 2 * E;
    unsigned short* kpb = pT + 524288;
    unsigned short* wqb = kpb + 524288;
    unsigned short* wkb = wqb + 1048576;
    unsigned short* wmb = wkb + 1048576;
    unsigned short* w1b = wmb + 1048576;
    unsigned short* w2b = w1b + 4194304;
    float* bqp = (float*)(w2b + 2097152);
    float* bkp = bqp + 1024;
    float* kpacc = (float*)ht;  // kp split-K partials alias ht (not yet live)

    cvt_transpose_xs<<<dim3(128, 32, 8), 256, 0, stream>>>(x, srcp, xt, st);
    cvt_transpose<<<dim3(4, 128, 1), 256, 0, stream>>>(proj, pT, 4096, 128);
    prep_weights<<<9220, 256, 0, stream>>>(Wq, Wk, Wm, W1, W2, bq, bk,
                                           wqb, wkb, wmb, w1b, w2b, bqp, bkp);

    // q = Wq @ x           (M=4096 seq, N'=1024 out-ch, K=1024)
    gemm256<1024, 1024, 1024, 1024, false><<<dim3(4, 16, 4), 512, 0, stream>>>(
        xt, nullptr, 1024, wqb, qt, nullptr,
        4096LL * 1024, 0LL, 4096LL * 1024, nullptr, bqp,
        nullptr, nullptr, nullptr, nullptr);
    // kc = Wk @ source     (M=1024 out-ch, N'=4096 seq, K=1024)
    gemm256<1024, 1024, 4096, 1024, false><<<dim3(16, 4, 4), 512, 0, stream>>>(
        wkb, nullptr, 1024, st, kc, nullptr,
        0LL, 4096LL * 1024, 1024LL * 4096, bkp, nullptr,
        nullptr, nullptr, nullptr, nullptr);
    // kp projection: N'=128 too narrow for the 256-tile — keep 128-tile split-K.
    gemm_bt<4096, 4096, 128, 4096, 8, false><<<dim3(1, 8, 32), 256, 0, stream>>>(
        kc, nullptr, 4096, pT, nullptr, kpacc,
        1024LL * 4096, 0LL, 1024LL * 128, nullptr, nullptr,
        nullptr, nullptr, nullptr, nullptr);
    reduce_kp<<<512, 256, 0, stream>>>(kpacc, kpb);
    attn_fused<<<dim3(32, 16, 4), 256, 0, stream>>>(qt, kpb, qt);
    // merge                (M=4096 seq, N'=1024, K=1024)
    gemm256<1024, 1024, 1024, 1024, false><<<dim3(4, 16, 4), 512, 0, stream>>>(
        qt, nullptr, 1024, wmb, st, nullptr,
        4096LL * 1024, 0LL, 4096LL * 1024, nullptr, bm,
        nullptr, nullptr, nullptr, nullptr);
    // mlp1 + BN + ReLU     (M=4096, N'=2048, K=2048 concat)
    gemm256<1024, 2048, 2048, 2048, true><<<dim3(8, 16, 4), 512, 0, stream>>>(
        xt, st, 1024, w1b, ht, nullptr,
        4096LL * 1024, 0LL, 4096LL * 2048, nullptr, b1,
        gam, bet, mu, var);
    // mlp2 -> f32 out      (M=1024 out-ch, N'=4096 seq, K=2048)
    gemm256<2048, 2048, 4096, 2048, false><<<dim3(16, 4, 4), 512, 0, stream>>>(
        w2b, nullptr, 2048, ht, nullptr, out,
        0LL, 4096LL * 2048, 1024LL * 4096, b2, nullptr,
        nullptr, nullptr, nullptr, nullptr);
}

// Round 5
// 616.634 us; speedup vs baseline: 1.8822x; 1.8822x over previous
//
#include <hip/hip_runtime.h>
#include <stdint.h>

typedef __bf16 bf16x8 __attribute__((ext_vector_type(8)));
typedef float f32x4 __attribute__((ext_vector_type(4)));

__device__ __forceinline__ unsigned short f2bf(float f) {
    union { float f; uint32_t i; } v;
    v.f = f;
    uint32_t x = v.i;
    return (unsigned short)((x + 0x7FFFu + ((x >> 16) & 1u)) >> 16);  // RNE
}

// async global->LDS, 16B per lane. LDS dest is wave-uniform base + lane*16;
// the GLOBAL source address is per-lane free (this is what enables swizzling).
typedef __attribute__((address_space(3))) unsigned int lds_u32;
typedef __attribute__((address_space(1))) const unsigned int glob_u32;
__device__ __forceinline__ void gld16(const unsigned short* g, unsigned short* l) {
    __builtin_amdgcn_global_load_lds((glob_u32*)g, (lds_u32*)l, 16, 0, 0);
}

// ---------------------------------------------------------------------------
// All weight prep in ONE launch (range-dispatch on blockIdx.x, 9220 blocks).
// ---------------------------------------------------------------------------
__global__ __launch_bounds__(256) void prep_weights(
    const float* __restrict__ Wq, const float* __restrict__ Wk,
    const float* __restrict__ Wm, const float* __restrict__ W1,
    const float* __restrict__ W2, const float* __restrict__ bq,
    const float* __restrict__ bk,
    unsigned short* __restrict__ wqb, unsigned short* __restrict__ wkb,
    unsigned short* __restrict__ wmb, unsigned short* __restrict__ w1b,
    unsigned short* __restrict__ w2b, float* __restrict__ bqp,
    float* __restrict__ bkp)
{
    const int b = blockIdx.x, t = threadIdx.x;
    if (b < 2048) {
        const float* in = (b < 1024) ? Wq : Wk;
        unsigned short* out = (b < 1024) ? wqb : wkb;
        const int i = ((b & 1023) * 256 + t) * 4;
        const int row = i >> 10, col = i & 1023;
        const float4 v = *(const float4*)(in + ((row & 63) * 16 + (row >> 6)) * 1024 + col);
        out[i + 0] = f2bf(v.x); out[i + 1] = f2bf(v.y);
        out[i + 2] = f2bf(v.z); out[i + 3] = f2bf(v.w);
    } else if (b < 3072) {
        const int i = ((b - 2048) * 256 + t) * 4;
        const int row = i >> 10, c0 = i & 1023;
        const float* r = Wm + (size_t)row * 1024;
#pragma unroll
        for (int j = 0; j < 4; ++j) {
            const int c = c0 + j;
            wmb[i + j] = f2bf(r[(c & 63) * 16 + (c >> 6)]);
        }
    } else if (b < 7168) {
        const int i = ((b - 3072) * 256 + t) * 4;
        const float4 v = *(const float4*)(W1 + i);
        w1b[i + 0] = f2bf(v.x); w1b[i + 1] = f2bf(v.y);
        w1b[i + 2] = f2bf(v.z); w1b[i + 3] = f2bf(v.w);
    } else if (b < 9216) {
        const int i = ((b - 7168) * 256 + t) * 4;
        const float4 v = *(const float4*)(W2 + i);
        w2b[i + 0] = f2bf(v.x); w2b[i + 1] = f2bf(v.y);
        w2b[i + 2] = f2bf(v.z); w2b[i + 3] = f2bf(v.w);
    } else {
        const int o = (b - 9216) * 256 + t;
        const int src = (o & 63) * 16 + (o >> 6);
        bqp[o] = bq[src];
        bkp[o] = bk[src];
    }
}

// ---------------------------------------------------------------------------
// f32 [R][C] -> bf16 [C][R], batched over blockIdx.z (proj).
// ---------------------------------------------------------------------------
__global__ __launch_bounds__(256) void cvt_transpose(
    const float* __restrict__ in, unsigned short* __restrict__ out,
    int R, int C)
{
    __shared__ unsigned short tile[32][33];
    const size_t bo = (size_t)blockIdx.z * R * C;
    const int c0 = blockIdx.x * 32, r0 = blockIdx.y * 32;
    const int tx = threadIdx.x & 31, ty = threadIdx.x >> 5;
#pragma unroll
    for (int i = 0; i < 4; ++i)
        tile[ty + i * 8][tx] = f2bf(in[bo + (size_t)(r0 + ty + i * 8) * C + (c0 + tx)]);
    __syncthreads();
#pragma unroll
    for (int i = 0; i < 4; ++i)
        out[bo + (size_t)(c0 + ty + i * 8) * R + (r0 + tx)] = tile[tx][ty + i * 8];
}

// Fused x + source transpose: z = tensor*4 + batch.
__global__ __launch_bounds__(256) void cvt_transpose_xs(
    const float* __restrict__ x, const float* __restrict__ s,
    unsigned short* __restrict__ xt, unsigned short* __restrict__ st)
{
    __shared__ unsigned short tile[32][33];
    const int z = blockIdx.z;
    const float* in = (z < 4) ? x : s;
    unsigned short* out = (z < 4) ? xt : st;
    const size_t bo = (size_t)(z & 3) * 1024 * 4096;
    const int c0 = blockIdx.x * 32, r0 = blockIdx.y * 32;
    const int tx = threadIdx.x & 31, ty = threadIdx.x >> 5;
#pragma unroll
    for (int i = 0; i < 4; ++i)
        tile[ty + i * 8][tx] = f2bf(in[bo + (size_t)(r0 + ty + i * 8) * 4096 + (c0 + tx)]);
    __syncthreads();
#pragma unroll
    for (int i = 0; i < 4; ++i)
        out[bo + (size_t)(c0 + ty + i * 8) * 1024 + (r0 + tx)] = tile[tx][ty + i * 8];
}

// ---------------------------------------------------------------------------
// OLD 128x128 2-barrier GEMM. Kept ONLY for the kp projection (N'=128 < 256).
// ---------------------------------------------------------------------------
template<int LDA, int LDB, int LDC, int KD, int SPLIT, bool CONCAT>
__global__ __launch_bounds__(256) void gemm_bt(
    const unsigned short* __restrict__ A,
    const unsigned short* __restrict__ A2, int K1,
    const unsigned short* __restrict__ BT,
    unsigned short* __restrict__ C, float* __restrict__ Cf,
    long long strideA, long long strideB, long long strideC,
    const float* __restrict__ bias_m,
    const float* __restrict__ bias_n,
    const float* __restrict__ bn_g,
    const float* __restrict__ bn_b,
    const float* __restrict__ bn_mu,
    const float* __restrict__ bn_var)
{
    constexpr int KPB = KD / SPLIT;
    __shared__ __align__(16) unsigned short As[128 * 64];
    __shared__ __align__(16) unsigned short Bs[128 * 64];

    const int z = blockIdx.z;
    const int batch = z / SPLIT;
    const int kbase = (z % SPLIT) * KPB;
    const int m0 = blockIdx.y * 128, n0 = blockIdx.x * 128;
    const unsigned short* Ab  = A + (size_t)batch * strideA;
    const unsigned short* A2b = CONCAT ? A2 + (size_t)batch * strideA
                                       : (const unsigned short*)0;
    const unsigned short* Bb = BT + (size_t)batch * strideB;

    const int t = threadIdx.x;
    const int lane = t & 63, wid = t >> 6;
    const int wm = wid >> 1, wn = wid & 1;
    const int r16 = lane & 15, quad = lane >> 4;

    f32x4 acc[4][4];
    const f32x4 zf = {0.f, 0.f, 0.f, 0.f};
#pragma unroll
    for (int i = 0; i < 4; ++i)
#pragma unroll
        for (int j = 0; j < 4; ++j) acc[i][j] = zf;

    for (int kt = kbase; kt < kbase + KPB; kt += 64) {
        const unsigned short* Asrc = Ab;
        int kk = kt;
        if (CONCAT && kt >= K1) { Asrc = A2b; kk = kt - K1; }
#pragma unroll
        for (int i = 0; i < 4; ++i) {
            const int p = i * 256 + t;
            const int row = p >> 3, slot = p & 7;
            const int kc = (slot ^ (row & 7)) * 8;
            gld16(&Asrc[(size_t)(m0 + row) * LDA + kk + kc], &As[p * 8]);
            gld16(&Bb[(size_t)(n0 + row) * LDB + kt + kc], &Bs[p * 8]);
        }
        __syncthreads();
#pragma unroll
        for (int s = 0; s < 2; ++s) {
            bf16x8 af[4], bfb[4];
#pragma unroll
            for (int i = 0; i < 4; ++i) {
                const int ra = wm * 64 + i * 16 + r16;
                const int rb = wn * 64 + i * 16 + r16;
                af[i]  = *(const bf16x8*)&As[(ra * 8 + ((s * 4 + quad) ^ (ra & 7))) * 8];
                bfb[i] = *(const bf16x8*)&Bs[(rb * 8 + ((s * 4 + quad) ^ (rb & 7))) * 8];
            }
#pragma unroll
            for (int mi = 0; mi < 4; ++mi)
#pragma unroll
                for (int ni = 0; ni < 4; ++ni)
                    acc[mi][ni] = __builtin_amdgcn_mfma_f32_16x16x32_bf16(
                        af[mi], bfb[ni], acc[mi][ni], 0, 0, 0);
        }
        __syncthreads();
    }

    unsigned short* Cb = C ? C + (size_t)z * strideC : (unsigned short*)0;
    float* Cfb = Cf ? Cf + (size_t)z * strideC : (float*)0;
    const bool has_bn = (bn_g != 0);
#pragma unroll
    for (int ni = 0; ni < 4; ++ni) {
        const int gn = n0 + wn * 64 + ni * 16 + r16;
        const float addn = bias_n ? bias_n[gn] : 0.f;
        float g = 1.f, bb = 0.f, mu = 0.f, rstd = 1.f;
        if (has_bn) {
            g = bn_g[gn]; bb = bn_b[gn]; mu = bn_mu[gn];
            rstd = rsqrtf(bn_var[gn] + 1e-3f);
        }
#pragma unroll
        for (int mi = 0; mi < 4; ++mi) {
            const int gm0 = m0 + wm * 64 + mi * 16 + quad * 4;
#pragma unroll
            for (int r = 0; r < 4; ++r) {
                float v = acc[mi][ni][r] + addn;
                if (bias_m) v += bias_m[gm0 + r];
                if (has_bn) { v = g * (v - mu) * rstd + bb; v = fmaxf(v, 0.f); }
                const size_t idx = (size_t)(gm0 + r) * LDC + gn;
                if (Cfb) Cfb[idx] = v;
                else     Cb[idx]  = f2bf(v);
            }
        }
    }
}

// ---------------------------------------------------------------------------
// 256x256 GEMM, TWO-phase K-step (8 waves 2Mx4N, BK=64, dbuf LDS 128 KiB).
// = round-3 kernel (v3, proven) with TWO changes:
//
// (1) Per-XCD RECTANGULAR tile mapping (template RN x RM, n-cols x m-rows).
//     r1-r3 showed schedule-invariant ~152 us => staging-BW-bound, not
//     sync-bound. The binding bytes are the L3-sourced slices of the LARGE
//     operand. Old remap degenerated to 8n x 1m rectangles for gx=16 grids
//     (kc, mlp2): ZERO B-slice reuse inside an XCD. New mapping gives each
//     XCD an RN x RM rectangle; a slice of the large operand is requested
//     by RM (or RN) K-synchronized blocks on the same XCD: 1 L3 miss +
//     rest L2 hits. Orientation per GEMM: reuse the big operand.
// (2) Prologue waits vmcnt(0) (r3's vmcnt(2) left B rows 128-255
//     unconfirmed before first read; compiler conservatism masked it).
// ---------------------------------------------------------------------------
#define BAR   __builtin_amdgcn_s_barrier()
#define LGKM0 asm volatile("s_waitcnt lgkmcnt(0)" ::: "memory")
#define PRIO1 __builtin_amdgcn_s_setprio(1)
#define PRIO0 __builtin_amdgcn_s_setprio(0)

#define ST_A(dst, kt, i0, i1) do {                                          \
    const unsigned short* S_ = Ab; long long kk_ = (kt);                    \
    if (CONCAT && (kt) >= K1) { S_ = A2b; kk_ = (kt) - K1; }                \
    gld16(&S_[offA[i0] + kk_], (dst) + po[i0]);                             \
    gld16(&S_[offA[i1] + kk_], (dst) + po[i1]); } while (0)

#define ST_B(dst, kt, i0, i1) do {                                          \
    gld16(&Bb[offB[i0] + (kt)], (dst) + po[i0]);                            \
    gld16(&Bb[offB[i1] + (kt)], (dst) + po[i1]); } while (0)

#define RD_A(mh, AC) do {                                                   \
    _Pragma("unroll") for (int mi = 0; mi < 4; ++mi) {                      \
        const int ra = wm * 128 + (mh) * 64 + mi * 16 + r16;                \
        _Pragma("unroll") for (int ks = 0; ks < 2; ++ks) {                  \
            const int c_ = ks * 4 + quad;                                   \
            a[mi][ks] = *(const bf16x8*)&(AC)[(ra * 8 + (c_ ^ (ra & 7))) * 8]; \
        } } } while (0)

#define RD_B(np, BC) do {                                                   \
    _Pragma("unroll") for (int i = 0; i < 2; ++i) {                         \
        const int rb = wn * 64 + ((np) * 2 + i) * 16 + r16;                 \
        _Pragma("unroll") for (int ks = 0; ks < 2; ++ks) {                  \
            const int c_ = ks * 4 + quad;                                   \
            b[(np) * 2 + i][ks] = *(const bf16x8*)&(BC)[(rb * 8 + (c_ ^ (rb & 7))) * 8]; \
        } } } while (0)

#define MFMA_PH(mh, np) do {                                                \
    _Pragma("unroll") for (int mi = 0; mi < 4; ++mi)                        \
    _Pragma("unroll") for (int i = 0; i < 2; ++i)                           \
    _Pragma("unroll") for (int ks = 0; ks < 2; ++ks)                        \
        acc[(mh) * 4 + mi][(np) * 2 + i] =                                  \
            __builtin_amdgcn_mfma_f32_16x16x32_bf16(                        \
                a[mi][ks], b[(np) * 2 + i][ks],                             \
                acc[(mh) * 4 + mi][(np) * 2 + i], 0, 0, 0); } while (0)

#define TILE_BODY(XV, AC, BC, AN, BN_) do {                                 \
    const int kt1_ = ((XV) + 1) * 64;                                       \
    const bool g1_ = ((XV) + 1) < nt;                                       \
    /* phase A: A(mh0)+all-B reads; stage U0,U1,U2(X+1) -> next buf */      \
    RD_A(0, AC); RD_B(0, BC); RD_B(1, BC);                                  \
    if (g1_) { ST_A(AN, kt1_, 0, 2); ST_B(BN_, kt1_, 0, 1);                 \
               ST_B(BN_, kt1_, 2, 3);                                       \
               asm volatile("s_waitcnt vmcnt(6)" ::: "memory"); }           \
    else     { asm volatile("s_waitcnt vmcnt(0)" ::: "memory"); }           \
    BAR; LGKM0; PRIO1; MFMA_PH(0, 0); MFMA_PH(0, 1); PRIO0; BAR;            \
    /* phase B: A(mh1) reads; stage U3(X+1) -> next buf */                  \
    RD_A(1, AC);                                                            \
    if (g1_) { ST_A(AN, kt1_, 1, 3);                                        \
               asm volatile("s_waitcnt vmcnt(2)" ::: "memory"); }           \
    else     { asm volatile("s_waitcnt vmcnt(0)" ::: "memory"); }           \
    BAR; LGKM0; PRIO1; MFMA_PH(1, 1); MFMA_PH(1, 0); PRIO0; BAR;            \
} while (0)

template<int LDA, int LDB, int LDC, int KD, int GX, int RN, int RM, bool CONCAT>
__global__ __launch_bounds__(512, 2) void gemm256(
    const unsigned short* __restrict__ A,
    const unsigned short* __restrict__ A2, int K1,
    const unsigned short* __restrict__ BT,
    unsigned short* __restrict__ C, float* __restrict__ Cf,
    long long strideA, long long strideB, long long strideC,
    const float* __restrict__ bias_m,
    const float* __restrict__ bias_n,
    const float* __restrict__ bn_g,
    const float* __restrict__ bn_b,
    const float* __restrict__ bn_mu,
    const float* __restrict__ bn_var)
{
    static_assert(KD % 128 == 0, "nt must be even");
    constexpr int nt = KD / 64;
    constexpr int TILE = 256 * 64;
    __shared__ __align__(16) unsigned short As0[TILE];
    __shared__ __align__(16) unsigned short As1[TILE];
    __shared__ __align__(16) unsigned short Bs0[TILE];
    __shared__ __align__(16) unsigned short Bs1[TILE];

    const int batch = blockIdx.z;
    // Per-XCD rectangle RN x RM. XCD = flat blockIdx & 7 (nwg % 8 == 0 for
    // all grids here, and z*nwg == 0 mod 8, so xcd is z-invariant).
    constexpr int CX = GX / RN;          // XCD grid columns (1, 2, 4 or 8)
    const int f = blockIdx.y * GX + blockIdx.x;
    const int xcd = f & 7, local = f >> 3;
    const int xc = xcd % CX, xr = xcd / CX;
    const int n0 = (xc * RN + (local % RN)) * 256;
    const int m0 = (xr * RM + (local / RN)) * 256;

    const unsigned short* Ab  = A + (size_t)batch * strideA;
    const unsigned short* A2b = CONCAT ? A2 + (size_t)batch * strideA
                                       : (const unsigned short*)0;
    const unsigned short* Bb  = BT + (size_t)batch * strideB;

    const int t = threadIdx.x;
    const int lane = t & 63, wid = t >> 6;
    const int wm = wid >> 2, wn = wid & 3;       // 2 x 4 wave grid
    const int r16 = lane & 15, quad = lane >> 4;

    // Precomputed staging offsets (statically indexed only).
    long long offA[4], offB[4];
    int po[4];
#pragma unroll
    for (int i = 0; i < 4; ++i) {
        const int p = i * 512 + t, row = p >> 3;
        const int kc = ((p & 7) ^ (row & 7)) * 8;
        po[i] = p * 8;
        offA[i] = (long long)(m0 + row) * LDA + kc;
        offB[i] = (long long)(n0 + row) * LDB + kc;
    }

    f32x4 acc[8][4];
    const f32x4 zf = {0.f, 0.f, 0.f, 0.f};
#pragma unroll
    for (int i = 0; i < 8; ++i)
#pragma unroll
        for (int j = 0; j < 4; ++j) acc[i][j] = zf;

    bf16x8 a[4][2], b[4][2];

    // Prologue: all 4 units of T0; vmcnt(0) so BOTH phases of tile 0 read
    // fully-landed data (r3's vmcnt(2) under-waited; fixed).
    ST_A(As0, 0, 0, 2);
    ST_B(Bs0, 0, 0, 1);
    ST_B(Bs0, 0, 2, 3);
    ST_A(As0, 0, 1, 3);
    asm volatile("s_waitcnt vmcnt(0)" ::: "memory");
    BAR;

#pragma unroll 1
    for (int X2 = 0; X2 < nt; X2 += 2) {
        TILE_BODY(X2,     As0, Bs0, As1, Bs1);
        TILE_BODY(X2 + 1, As1, Bs1, As0, Bs0);
    }

    unsigned short* Cb = C ? C + (size_t)batch * strideC : (unsigned short*)0;
    float* Cfb = Cf ? Cf + (size_t)batch * strideC : (float*)0;
    const bool has_bn = (bn_g != 0);

    // Per-ni column params hoisted; ni innermost so both 32B halves of each
    // 64B line are written back-to-back (write-combining; bf16 C path).
    float addn4[4], g4[4], b4[4], mu4[4], rs4[4];
#pragma unroll
    for (int ni = 0; ni < 4; ++ni) {
        const int gn = n0 + wn * 64 + ni * 16 + r16;
        addn4[ni] = bias_n ? bias_n[gn] : 0.f;
        if (has_bn) {
            g4[ni] = bn_g[gn]; b4[ni] = bn_b[gn]; mu4[ni] = bn_mu[gn];
            rs4[ni] = rsqrtf(bn_var[gn] + 1e-3f);
        }
    }
#pragma unroll
    for (int mi = 0; mi < 8; ++mi) {
        const int gm0 = m0 + wm * 128 + mi * 16 + quad * 4;
#pragma unroll
        for (int r = 0; r < 4; ++r) {
            const float bm_ = bias_m ? bias_m[gm0 + r] : 0.f;
            const size_t rowb = (size_t)(gm0 + r) * LDC + n0 + wn * 64 + r16;
#pragma unroll
            for (int ni = 0; ni < 4; ++ni) {
                float v = acc[mi][ni][r] + addn4[ni] + bm_;
                if (has_bn) {
                    v = g4[ni] * (v - mu4[ni]) * rs4[ni] + b4[ni];
                    v = fmaxf(v, 0.f);
                }
                if (Cfb) Cfb[rowb + ni * 16] = v;
                else     Cb[rowb + ni * 16]  = f2bf(v);
            }
        }
    }
}

#undef TILE_BODY
#undef MFMA_PH
#undef RD_B
#undef RD_A
#undef ST_B
#undef ST_A
#undef PRIO0
#undef PRIO1
#undef LGKM0
#undef BAR

// kp split-K reduce: kpb[b][j] = bf16( sum_p acc[b*8+p][j] )
__global__ __launch_bounds__(256) void reduce_kp(
    const float* __restrict__ acc, unsigned short* __restrict__ kpb)
{
    const int j = (blockIdx.x * 256 + threadIdx.x) * 4;
    const int b = j >> 17, jj = j & 131071;
    const float* base = acc + (size_t)b * 8 * 131072 + jj;
    float4 s = *(const float4*)base;
#pragma unroll
    for (int p = 1; p < 8; ++p) {
        const float4 v = *(const float4*)(base + (size_t)p * 131072);
        s.x += v.x; s.y += v.y; s.z += v.z; s.w += v.w;
    }
    kpb[j + 0] = f2bf(s.x); kpb[j + 1] = f2bf(s.y);
    kpb[j + 2] = f2bf(s.z); kpb[j + 3] = f2bf(s.w);
}

// ---------------------------------------------------------------------------
// MFMA flash-attention (unchanged; channel order o' = h*64+dh).
// ---------------------------------------------------------------------------
__global__ __launch_bounds__(256) void attn_fused(
    const unsigned short* __restrict__ qT,
    const unsigned short* __restrict__ kp,
    unsigned short* __restrict__ msgT)
{
    constexpr int QS = 72, KS = 72, VS = 136, PS = 136;
    __shared__ __align__(16) unsigned short QKP[128 * QS + 128 * KS];
    __shared__ __align__(16) unsigned short Vs[64 * VS];
    unsigned short* Qs = QKP;
    unsigned short* Ks = QKP + 128 * QS;
    unsigned short* Ps = QKP;

    const int t = threadIdx.x;
    const int lane = t & 63, w = t >> 6;
    const int r16 = lane & 15, quad = lane >> 4;
    const int h = blockIdx.y, n0 = blockIdx.x * 128;
    const size_t b = blockIdx.z;

    const unsigned short* qbase = qT + (b * 4096 + n0) * 1024 + h * 64;
    const unsigned short* kbase = kp + (b * 1024 + h * 64) * 128;

#pragma unroll
    for (int i = 0; i < 4; ++i) {
        const int c = i * 256 + t;
        const int n = c >> 3, dh0 = (c & 7) * 8;
        *(int4*)&Qs[n * QS + dh0] = *(const int4*)&qbase[(size_t)n * 1024 + dh0];
    }
#pragma unroll
    for (int i = 0; i < 4; ++i) {
        const int c = i * 256 + t;
        const int kkq = c & 3, dh = (c >> 2) & 63, kkh = c >> 8;
        const int kk0 = kkh * 32 + kkq * 8;
        const bf16x8 v = *(const bf16x8*)&kbase[(size_t)dh * 128 + kk0];
        *(bf16x8*)&Vs[dh * VS + kk0] = v;
        const unsigned short* vs = (const unsigned short*)&v;
#pragma unroll
        for (int j = 0; j < 8; ++j) Ks[(kk0 + j) * KS + dh] = vs[j];
    }
    __syncthreads();

    f32x4 S[2][8];
    const f32x4 zf = {0.f, 0.f, 0.f, 0.f};
#pragma unroll
    for (int mi = 0; mi < 2; ++mi)
#pragma unroll
        for (int ni = 0; ni < 8; ++ni) S[mi][ni] = zf;

    bf16x8 aq[2][2];
#pragma unroll
    for (int mi = 0; mi < 2; ++mi)
#pragma unroll
        for (int ks = 0; ks < 2; ++ks)
            aq[mi][ks] = *(const bf16x8*)&Qs[(w * 32 + mi * 16 + r16) * QS + ks * 32 + quad * 8];
#pragma unroll
    for (int ni = 0; ni < 8; ++ni) {
        const bf16x8 b0 = *(const bf16x8*)&Ks[(ni * 16 + r16) * KS + quad * 8];
        const bf16x8 b1 = *(const bf16x8*)&Ks[(ni * 16 + r16) * KS + 32 + quad * 8];
#pragma unroll
        for (int mi = 0; mi < 2; ++mi) {
            S[mi][ni] = __builtin_amdgcn_mfma_f32_16x16x32_bf16(aq[mi][0], b0, S[mi][ni], 0, 0, 0);
            S[mi][ni] = __builtin_amdgcn_mfma_f32_16x16x32_bf16(aq[mi][1], b1, S[mi][ni], 0, 0, 0);
        }
    }

    __syncthreads();

    float linv[2][4];
#pragma unroll
    for (int mi = 0; mi < 2; ++mi) {
        float e[8][4];
        float rs0 = 0.f, rs1 = 0.f, rs2 = 0.f, rs3 = 0.f;
#pragma unroll
        for (int ni = 0; ni < 8; ++ni) {
            e[ni][0] = __expf(S[mi][ni][0] * 0.125f); rs0 += e[ni][0];
            e[ni][1] = __expf(S[mi][ni][1] * 0.125f); rs1 += e[ni][1];
            e[ni][2] = __expf(S[mi][ni][2] * 0.125f); rs2 += e[ni][2];
            e[ni][3] = __expf(S[mi][ni][3] * 0.125f); rs3 += e[ni][3];
        }
        float rs[4] = {rs0, rs1, rs2, rs3};
#pragma unroll
        for (int r = 0; r < 4; ++r) {
            float s = rs[r];
            s += __shfl_xor(s, 1); s += __shfl_xor(s, 2);
            s += __shfl_xor(s, 4); s += __shfl_xor(s, 8);
            linv[mi][r] = 1.f / s;
        }
#pragma unroll
        for (int ni = 0; ni < 8; ++ni)
#pragma unroll
            for (int r = 0; r < 4; ++r)
                Ps[(w * 32 + mi * 16 + quad * 4 + r) * PS + ni * 16 + r16] = f2bf(e[ni][r]);
    }
    __syncthreads();

    f32x4 O[2][4];
#pragma unroll
    for (int mi = 0; mi < 2; ++mi)
#pragma unroll
        for (int ni = 0; ni < 4; ++ni) O[mi][ni] = zf;

    bf16x8 ap[2][4];
#pragma unroll
    for (int mi = 0; mi < 2; ++mi)
#pragma unroll
        for (int ks = 0; ks < 4; ++ks)
            ap[mi][ks] = *(const bf16x8*)&Ps[(w * 32 + mi * 16 + r16) * PS + ks * 32 + quad * 8];
#pragma unroll
    for (int ni = 0; ni < 4; ++ni)
#pragma unroll
        for (int ks = 0; ks < 4; ++ks) {
            const bf16x8 bv = *(const bf16x8*)&Vs[(ni * 16 + r16) * VS + ks * 32 + quad * 8];
#pragma unroll
            for (int mi = 0; mi < 2; ++mi)
                O[mi][ni] = __builtin_amdgcn_mfma_f32_16x16x32_bf16(ap[mi][ks], bv, O[mi][ni], 0, 0, 0);
        }

    unsigned short* ob = msgT + (b * 4096 + n0) * 1024 + h * 64;
#pragma unroll
    for (int mi = 0; mi < 2; ++mi)
#pragma unroll
        for (int ni = 0; ni < 4; ++ni)
#pragma unroll
            for (int r = 0; r < 4; ++r)
                ob[(size_t)(w * 32 + mi * 16 + quad * 4 + r) * 1024 + ni * 16 + r16] =
                    f2bf(O[mi][ni][r] * linv[mi][r]);
}

// ---------------------------------------------------------------------------
extern "C" void kernel_launch(void* const* d_in, const int* in_sizes, int n_in,
                              void* d_out, int out_size, void* d_ws, size_t ws_size,
                              hipStream_t stream)
{
    (void)in_sizes; (void)n_in; (void)out_size; (void)ws_size;
    const float* x    = (const float*)d_in[0];
    const float* srcp = (const float*)d_in[1];
    const float* Wq   = (const float*)d_in[2];
    const float* bq   = (const float*)d_in[3];
    const float* Wk   = (const float*)d_in[4];
    const float* bk   = (const float*)d_in[5];
    const float* proj = (const float*)d_in[6];
    const float* Wm   = (const float*)d_in[7];
    const float* bm   = (const float*)d_in[8];
    const float* W1   = (const float*)d_in[9];
    const float* b1   = (const float*)d_in[10];
    const float* gam  = (const float*)d_in[11];
    const float* bet  = (const float*)d_in[12];
    const float* mu   = (const float*)d_in[13];
    const float* var  = (const float*)d_in[14];
    const float* W2   = (const float*)d_in[15];
    const float* b2   = (const float*)d_in[16];
    float* out = (float*)d_out;
    unsigned short* ws = (unsigned short*)d_ws;

    const long long E = 16777216LL;  // 4*4096*1024
    unsigned short* xt  = ws;
    unsigned short* st  = xt + E;
    unsigned short* qt  = st + E;
    unsigned short* kc  = qt + E;
    unsigned short* ht  = kc + E;
    unsigned short* pT  = ht + 2 * E;
    unsigned short* kpb = pT + 524288;
    unsigned short* wqb = kpb + 524288;
    unsigned short* wkb = wqb + 1048576;
    unsigned short* wmb = wkb + 1048576;
    unsigned short* w1b = wmb + 1048576;
    unsigned short* w2b = w1b + 4194304;
    float* bqp = (float*)(w2b + 2097152);
    float* bkp = bqp + 1024;
    float* kpacc = (float*)ht;  // kp split-K partials alias ht (not yet live)

    cvt_transpose_xs<<<dim3(128, 32, 8), 256, 0, stream>>>(x, srcp, xt, st);
    cvt_transpose<<<dim3(4, 128, 1), 256, 0, stream>>>(proj, pT, 4096, 128);
    prep_weights<<<9220, 256, 0, stream>>>(Wq, Wk, Wm, W1, W2, bq, bk,
                                           wqb, wkb, wmb, w1b, w2b, bqp, bkp);

    // q = Wq @ x   (gx=4, gy=16; A=xt big -> rect 4n x 2m: A-slice reuse 4)
    gemm256<1024, 1024, 1024, 1024, 4, 4, 2, false><<<dim3(4, 16, 4), 512, 0, stream>>>(
        xt, nullptr, 1024, wqb, qt, nullptr,
        4096LL * 1024, 0LL, 4096LL * 1024, nullptr, bqp,
        nullptr, nullptr, nullptr, nullptr);
    // kc = Wk @ source  (gx=16, gy=4; B=st big -> rect 2n x 4m: B reuse 4)
    gemm256<1024, 1024, 4096, 1024, 16, 2, 4, false><<<dim3(16, 4, 4), 512, 0, stream>>>(
        wkb, nullptr, 1024, st, kc, nullptr,
        0LL, 4096LL * 1024, 1024LL * 4096, bkp, nullptr,
        nullptr, nullptr, nullptr, nullptr);
    // kp projection: N'=128 too narrow for the 256-tile — keep 128-tile split-K.
    gemm_bt<4096, 4096, 128, 4096, 8, false><<<dim3(1, 8, 32), 256, 0, stream>>>(
        kc, nullptr, 4096, pT, nullptr, kpacc,
        1024LL * 4096, 0LL, 1024LL * 128, nullptr, nullptr,
        nullptr, nullptr, nullptr, nullptr);
    reduce_kp<<<512, 256, 0, stream>>>(kpacc, kpb);
    attn_fused<<<dim3(32, 16, 4), 256, 0, stream>>>(qt, kpb, qt);
    // merge  (gx=4, gy=16; A=qt big -> rect 4n x 2m)
    gemm256<1024, 1024, 1024, 1024, 4, 4, 2, false><<<dim3(4, 16, 4), 512, 0, stream>>>(
        qt, nullptr, 1024, wmb, st, nullptr,
        4096LL * 1024, 0LL, 4096LL * 1024, nullptr, bm,
        nullptr, nullptr, nullptr, nullptr);
    // mlp1 + BN + ReLU  (gx=8, gy=16; A=xt/st big -> rect 8n x 2m: A reuse 8)
    gemm256<1024, 2048, 2048, 2048, 8, 8, 2, true><<<dim3(8, 16, 4), 512, 0, stream>>>(
        xt, st, 1024, w1b, ht, nullptr,
        4096LL * 1024, 0LL, 4096LL * 2048, nullptr, b1,
        gam, bet, mu, var);
    // mlp2 -> f32 out  (gx=16, gy=4; B=ht big -> rect 2n x 4m: B reuse 4)
    gemm256<2048, 2048, 4096, 2048, 16, 2, 4, false><<<dim3(16, 4, 4), 512, 0, stream>>>(
        w2b, nullptr, 2048, ht, nullptr, out,
        0LL, 4096LL * 2048, 1024LL * 4096, b2, nullptr,
        nullptr, nullptr, nullptr, nullptr);
}